// Round 5
// baseline (215.531 us; speedup 1.0000x reference)
//
#include <hip/hip_runtime.h>
#include <hip/hip_bf16.h>

#define H 512
#define NLAYERS 12
#define OUTF 256
#define BM 64
#define CAP 1024   // max edges per 64-row block (mean 512, 22 sigma headroom)

typedef unsigned short u16;
typedef unsigned int u32;
typedef u16 u16x8 __attribute__((ext_vector_type(8)));
typedef short s16x8 __attribute__((ext_vector_type(8)));
typedef float f32x4 __attribute__((ext_vector_type(4)));

__device__ __forceinline__ u16 f2bf(float f){
  u32 u = __float_as_uint(f);
  u32 r = (u + 0x7FFFu + ((u>>16)&1u)) >> 16;   // RTNE
  return (u16)r;
}

// ---- k_pre: [x0 gather + Sx] | [Wc transpose->bf16] | [row histogram] ---
__global__ __launch_bounds__(256) void k_pre(
    const float* __restrict__ sst, const int* __restrict__ node_idx,
    float* __restrict__ x0, float* __restrict__ Sx,
    const float* __restrict__ Wc, u16* __restrict__ wct,
    const int* __restrict__ arows, int* __restrict__ counts,
    int N, int E, int nbx0){
  __shared__ float tile[32][33];
  __shared__ float red[4];
  int b = blockIdx.x;
  int t = threadIdx.x;
  if (b < nbx0){
    int i = b*256 + t;
    float v = 0.f;
    if (i < N){ v = sst[node_idx[i]]; x0[i] = v; }
    #pragma unroll
    for (int o=32;o;o>>=1) v += __shfl_xor(v,o);
    int l = t & 63, w = t >> 6;
    if (l==0) red[w] = v;
    __syncthreads();
    if (t==0) atomicAdd(Sx, red[0]+red[1]+red[2]+red[3]);
  } else if (b < nbx0 + 256){
    int bb = b - nbx0;
    int bk = (bb & 15) * 32;    // k block
    int bh = (bb >> 4) * 32;    // h block
    int c = t & 31, r4 = t >> 5;
    #pragma unroll
    for (int p=0;p<4;p++){
      int kr = r4 + p*8;
      tile[kr][c] = Wc[(size_t)(bk+kr)*H + bh + c];
    }
    __syncthreads();
    #pragma unroll
    for (int p=0;p<4;p++){
      int hr = r4 + p*8;
      wct[(size_t)(bh+hr)*H + bk + c] = f2bf(tile[c][hr]);
    }
  } else {
    int e = (b - nbx0 - 256)*256 + t;
    if (e < E) atomicAdd(&counts[arows[e]], 1);
  }
}

// ---------------- exclusive scan of counts -> rowptr, cursor ------------
__global__ __launch_bounds__(1024) void k_scan(const int* __restrict__ counts,
                     int* __restrict__ rowptr, int* __restrict__ cursor, int N){
  __shared__ int s[1024];
  int t = threadIdx.x;
  const int CH = 48;                 // 48*1024 >= N; N multiple of 4
  int beg = t*CH, end = min(beg+CH, N);
  int sum = 0;
  for (int i=beg;i<end;i+=4){
    int4 v = *(const int4*)(counts+i);
    sum += v.x+v.y+v.z+v.w;
  }
  s[t] = sum; __syncthreads();
  for (int off=1; off<1024; off<<=1){
    int v = (t>=off) ? s[t-off] : 0;
    __syncthreads();
    s[t] += v;
    __syncthreads();
  }
  int run = s[t] - sum;
  for (int i=beg;i<end;i+=4){
    int4 v = *(const int4*)(counts+i);
    int4 rp; rp.x = run; rp.y = run+v.x; rp.z = rp.y+v.y; rp.w = rp.z+v.z;
    *(int4*)(rowptr+i) = rp;
    *(int4*)(cursor+i) = rp;
    run = rp.w + v.w;
  }
  if (t==1023) rowptr[N] = s[1023];
}

// ------- CSR fill (counting sort, packed 8B records) + y = adj@x0 -------
__global__ void k_fill(const int* __restrict__ rows, const int* __restrict__ cols,
                       const float* __restrict__ vals, const float* __restrict__ x0,
                       int* __restrict__ cursor, float* __restrict__ y,
                       int2* __restrict__ ev2, int E){
  int e = blockIdx.x*blockDim.x + threadIdx.x;
  if (e < E){
    int r = rows[e], c = cols[e];
    float v = vals[e];
    int pos = atomicAdd(&cursor[r], 1);
    ev2[pos] = make_int2(c, __float_as_int(v));
    atomicAdd(&y[r], v * x0[c]);
  }
}

// ---- FUSED: z-tile build (in LDS) + x1-pool + MFMA GEMM + colsum -------
// Block: 64 rows x all 512 cols. z-phase: thread t owns channel h=t for
// ALL rows -> block-uniform edge loop, zero divergence, W1/b1 in regs.
// z[r,h] = y[r] + sum_{e in row r} v_e * leaky(y[c_e]*W1[h] + b1[h])
// zlds layout: byte(r,h) = r*1024 + (2h ^ ((r&7)<<4))  [conflict-free both sides]
// GEMM phase: 8 waves, wave w = all 64 rows x cols [w*64, w*64+64), B from L2.
__global__ __launch_bounds__(512, 4) void k_fused(
    const int* __restrict__ rowptr, const int2* __restrict__ ev2,
    const float* __restrict__ y,
    const float* __restrict__ W1, const float* __restrict__ b1,
    const u16* __restrict__ wct, const float* __restrict__ bc,
    float* __restrict__ pooled_acc, int N)
{
  __shared__ __align__(16) unsigned char zlds[BM*1024];  // 64KB swizzled bf16 z
  __shared__ __align__(16) float2 evy[CAP];              // 8KB (v, y[c]) per edge
  __shared__ int rs[BM+1];
  __shared__ float y_r[BM];

  int t = threadIdx.x;
  int m0 = blockIdx.x * BM;
  int rows_valid = min(BM, N - m0);

  if (t <= BM) rs[t] = rowptr[min(m0 + t, N)];
  if (t < BM)  y_r[t] = (t < rows_valid) ? y[m0 + t] : 0.f;
  __syncthreads();

  int eb = rs[0];
  int ne = min(rs[BM] - eb, CAP);
  for (int j = t; j < ne; j += 512){
    int2 e = ev2[eb + j];
    evy[j] = make_float2(__int_as_float(e.y), y[e.x]);
  }
  __syncthreads();

  // ---- z phase + x1 pool: channel h = t, all rows, uniform schedule
  {
    float w = W1[t], b = b1[t];
    int hoff = t*2;
    float ps = 0.f;
    for (int r = 0; r < BM; ++r){
      int jb = min(rs[r] - eb, ne), je = min(rs[r+1] - eb, ne);
      float acc = 0.f;
      for (int j = jb; j < je; ++j){
        float2 e = evy[j];
        float s = fmaf(e.y, w, b);
        acc = fmaf(e.x, fmaxf(s, 0.01f*s), acc);
      }
      float yr = y_r[r];
      *(u16*)(zlds + r*1024 + (hoff ^ ((r&7)<<4))) = f2bf(acc + yr);
      if (r < rows_valid){
        float v = fmaf(yr, w, b);
        ps += fmaxf(v, 0.01f*v);
      }
    }
    atomicAdd(&pooled_acc[t], ps);
  }
  __syncthreads();

  // ---- GEMM phase: NO barriers; A LDS-resident, B streams from L2
  int lane = t & 63, wid = t >> 6;
  int r15 = lane & 15, rg = lane >> 4;
  int nc = wid * 64;
  int swz = (r15 & 7) << 4;
  f32x4 acc[4][4] = {};
  const u16* bp = wct + (size_t)(nc + r15)*H + rg*8;

  #pragma unroll 2
  for (int kt = 0; kt < 16; ++kt){
    s16x8 af[4], bf[4];
    #pragma unroll
    for (int m = 0; m < 4; ++m){
      int off = (m*16 + r15)*1024 + ((kt*64 + rg*16) ^ swz);
      af[m] = *(const s16x8*)(zlds + off);
    }
    #pragma unroll
    for (int n = 0; n < 4; ++n)
      bf[n] = *(const s16x8*)(bp + (size_t)n*16*H + kt*32);
    #pragma unroll
    for (int m = 0; m < 4; ++m)
      #pragma unroll
      for (int n = 0; n < 4; ++n)
        acc[m][n] = __builtin_amdgcn_mfma_f32_16x16x32_bf16(af[m], bf[n], acc[m][n], 0,0,0);
  }

  // ---- epilogue: leaky(acc + bc), masked column-sum -> pooled_acc
  #pragma unroll
  for (int n = 0; n < 4; ++n){
    int gc = nc + n*16 + r15;
    float bcv = bc[gc];
    float cs = 0.f;
    #pragma unroll
    for (int m = 0; m < 4; ++m){
      int r0 = m*16 + rg*4;
      #pragma unroll
      for (int j = 0; j < 4; ++j){
        if (r0 + j < rows_valid){
          float wv2 = acc[m][n][j] + bcv;
          cs += fmaxf(wv2, 0.01f*wv2);
        }
      }
    }
    cs += __shfl_xor(cs, 16);
    cs += __shfl_xor(cs, 32);
    if (rg == 0) atomicAdd(&pooled_acc[gc], cs);
  }
}

// ------- gamma/beta heads (finalizes pooled locally): 1 wave / row ------
__global__ __launch_bounds__(256) void k_heads(const float* __restrict__ pooled_acc,
        const float* __restrict__ Sx,
        const float* __restrict__ Wg, const float* __restrict__ bg,
        const float* __restrict__ Wb, const float* __restrict__ bb,
        float* __restrict__ out, float invN){
  __shared__ float sp[H];
  int t = threadIdx.x;
  float sx = Sx[0];
  sp[t]     = (pooled_acc[t]     + sx) * invN;
  sp[t+256] = (pooled_acc[t+256] + sx) * invN;
  __syncthreads();
  int wid = t >> 6, l = t & 63;
  int o = blockIdx.x*4 + wid;           // 0..6143
  int head = o / (NLAYERS*OUTF);        // 0=gamma 1=beta
  int rem  = o - head*(NLAYERS*OUTF);
  const float* W = (head ? Wb : Wg) + (size_t)rem * H;
  float4 wa = *(const float4*)(W + l*8);
  float4 wb = *(const float4*)(W + l*8 + 4);
  float4 pa = *(const float4*)(sp + l*8);
  float4 pb = *(const float4*)(sp + l*8 + 4);
  float acc = wa.x*pa.x + wa.y*pa.y + wa.z*pa.z + wa.w*pa.w
            + wb.x*pb.x + wb.y*pb.y + wb.z*pb.z + wb.w*pb.w;
  #pragma unroll
  for (int off=32; off; off>>=1) acc += __shfl_xor(acc, off);
  if (l == 0) out[o] = acc + (head ? bb : bg)[rem];
}

extern "C" void kernel_launch(void* const* d_in, const int* in_sizes, int n_in,
                              void* d_out, int out_size, void* d_ws, size_t ws_size,
                              hipStream_t stream){
  const float* sst      = (const float*)d_in[0];
  const int*   node_idx = (const int*)d_in[1];
  const int*   arows    = (const int*)d_in[2];
  const int*   acols    = (const int*)d_in[3];
  const float* avals    = (const float*)d_in[4];
  const float* W1       = (const float*)d_in[5];
  const float* b1       = (const float*)d_in[6];
  const float* Wc       = (const float*)d_in[7];
  const float* bc       = (const float*)d_in[8];
  const float* Wg       = (const float*)d_in[9];
  const float* bg       = (const float*)d_in[10];
  const float* Wb       = (const float*)d_in[11];
  const float* bb       = (const float*)d_in[12];

  const int N = in_sizes[1];
  const int E = in_sizes[2];

  char* w = (char*)d_ws;
  size_t off = 0;
  auto take = [&](size_t b)->char*{ char* p = w + off; off += (b + 255) & ~(size_t)255; return p; };

  size_t zero_words = (size_t)2*N + H + 1;     // y | counts | pooled_acc | Sx
  float* y          = (float*)take(zero_words*4);
  int*   counts     = (int*)(y + N);
  float* pooled_acc = y + 2*N;
  float* Sx         = pooled_acc + H;
  float* x0         = (float*)take((size_t)N*4);
  int*   rowptr     = (int*)take((size_t)(N+1)*4);
  int*   cursor     = (int*)take((size_t)N*4);
  int2*  ev2        = (int2*)take((size_t)E*8);
  u16*   wct        = (u16*)take((size_t)H*H*2);

  hipMemsetAsync(y, 0, zero_words*4, stream);

  int nbx0 = (N + 255)/256;
  int nbhist = (E + 255)/256;
  k_pre  <<<nbx0 + 256 + nbhist, 256, 0, stream>>>(sst, node_idx, x0, Sx,
                                                   Wc, wct, arows, counts, N, E, nbx0);
  k_scan <<<1, 1024, 0, stream>>>(counts, rowptr, cursor, N);
  k_fill <<<(E+255)/256, 256, 0, stream>>>(arows, acols, avals, x0, cursor, y, ev2, E);
  int nblk = (N + BM - 1) / BM;
  k_fused<<<nblk, 512, 0, stream>>>(rowptr, ev2, y, W1, b1, wct, bc, pooled_acc, N);
  k_heads<<<(2*NLAYERS*OUTF)/4, 256, 0, stream>>>(pooled_acc, Sx, Wg, bg, Wb, bb,
                                                  (float*)d_out, 1.0f/(float)N);
}

// Round 6
// 170.640 us; speedup vs baseline: 1.2631x; 1.2631x over previous
//
#include <hip/hip_runtime.h>
#include <hip/hip_bf16.h>

#define H 512
#define NLAYERS 12
#define OUTF 256
#define BM 64
#define CAP 1024   // max edges per 64-row block (mean 512, 22 sigma headroom)

typedef unsigned short u16;
typedef unsigned int u32;
typedef u16 u16x8 __attribute__((ext_vector_type(8)));
typedef short s16x8 __attribute__((ext_vector_type(8)));
typedef float f32x4 __attribute__((ext_vector_type(4)));

__device__ __forceinline__ u16 f2bf(float f){
  u32 u = __float_as_uint(f);
  u32 r = (u + 0x7FFFu + ((u>>16)&1u)) >> 16;   // RTNE
  return (u16)r;
}

// ---- k_pre: [x0 gather + Sx] | [Wc transpose->bf16] | [row histogram] ---
__global__ __launch_bounds__(256) void k_pre(
    const float* __restrict__ sst, const int* __restrict__ node_idx,
    float* __restrict__ x0, float* __restrict__ Sx,
    const float* __restrict__ Wc, u16* __restrict__ wct,
    const int* __restrict__ arows, int* __restrict__ counts,
    int N, int E, int nbx0){
  __shared__ float tile[32][33];
  __shared__ float red[4];
  int b = blockIdx.x;
  int t = threadIdx.x;
  if (b < nbx0){
    int i = b*256 + t;
    float v = 0.f;
    if (i < N){ v = sst[node_idx[i]]; x0[i] = v; }
    #pragma unroll
    for (int o=32;o;o>>=1) v += __shfl_xor(v,o);
    int l = t & 63, w = t >> 6;
    if (l==0) red[w] = v;
    __syncthreads();
    if (t==0) atomicAdd(Sx, red[0]+red[1]+red[2]+red[3]);
  } else if (b < nbx0 + 256){
    int bb = b - nbx0;
    int bk = (bb & 15) * 32;    // k block
    int bh = (bb >> 4) * 32;    // h block
    int c = t & 31, r4 = t >> 5;
    #pragma unroll
    for (int p=0;p<4;p++){
      int kr = r4 + p*8;
      tile[kr][c] = Wc[(size_t)(bk+kr)*H + bh + c];
    }
    __syncthreads();
    #pragma unroll
    for (int p=0;p<4;p++){
      int hr = r4 + p*8;
      wct[(size_t)(bh+hr)*H + bk + c] = f2bf(tile[c][hr]);
    }
  } else {
    int e = (b - nbx0 - 256)*256 + t;
    if (e < E) atomicAdd(&counts[arows[e]], 1);
  }
}

// ---------------- exclusive scan of counts -> rowptr, cursor ------------
__global__ __launch_bounds__(1024) void k_scan(const int* __restrict__ counts,
                     int* __restrict__ rowptr, int* __restrict__ cursor, int N){
  __shared__ int s[1024];
  int t = threadIdx.x;
  const int CH = 48;                 // 48*1024 >= N; N multiple of 4
  int beg = t*CH, end = min(beg+CH, N);
  int sum = 0;
  for (int i=beg;i<end;i+=4){
    int4 v = *(const int4*)(counts+i);
    sum += v.x+v.y+v.z+v.w;
  }
  s[t] = sum; __syncthreads();
  for (int off=1; off<1024; off<<=1){
    int v = (t>=off) ? s[t-off] : 0;
    __syncthreads();
    s[t] += v;
    __syncthreads();
  }
  int run = s[t] - sum;
  for (int i=beg;i<end;i+=4){
    int4 v = *(const int4*)(counts+i);
    int4 rp; rp.x = run; rp.y = run+v.x; rp.z = rp.y+v.y; rp.w = rp.z+v.z;
    *(int4*)(rowptr+i) = rp;
    *(int4*)(cursor+i) = rp;
    run = rp.w + v.w;
  }
  if (t==1023) rowptr[N] = s[1023];
}

// ------- CSR fill (counting sort, packed 8B records) + y = adj@x0 -------
__global__ void k_fill(const int* __restrict__ rows, const int* __restrict__ cols,
                       const float* __restrict__ vals, const float* __restrict__ x0,
                       int* __restrict__ cursor, float* __restrict__ y,
                       int2* __restrict__ ev2, int E){
  int e = blockIdx.x*blockDim.x + threadIdx.x;
  if (e < E){
    int r = rows[e], c = cols[e];
    float v = vals[e];
    int pos = atomicAdd(&cursor[r], 1);
    ev2[pos] = make_int2(c, __float_as_int(v));
    atomicAdd(&y[r], v * x0[c]);
  }
}

// ---- FUSED: z-tile build (in LDS) + MFMA GEMM + colsum + x1-pool -------
// z-phase: wave w owns rows 8w..8w+7; lane l owns channels 8l..8l+7.
//   -> edge index j uniform per wave (broadcast LDS read), 32 VALU per read,
//      unroll-4 edge batches, one u16x8 swizzled store per (row, lane).
// zlds layout: byte(r,h) = r*1024 + (2h ^ ((r&7)<<4))  [conflict-free r/w]
// GEMM phase: 8 waves, wave w = all 64 rows x cols [w*64,+64), B from L2,
//   NO barriers in K-loop. Epilogue folds bias+leaky+colsum AND x1-pool.
__global__ __launch_bounds__(512, 4) void k_fused(
    const int* __restrict__ rowptr, const int2* __restrict__ ev2,
    const float* __restrict__ y,
    const float* __restrict__ W1, const float* __restrict__ b1,
    const u16* __restrict__ wct, const float* __restrict__ bc,
    float* __restrict__ pooled_acc, int N)
{
  __shared__ __align__(16) unsigned char zlds[BM*1024];  // 64KB swizzled bf16 z
  __shared__ __align__(16) float2 evy[CAP];              // 8KB (v, y[c]) per edge
  __shared__ int rs[BM+1];
  __shared__ float y_r[BM];

  int t = threadIdx.x;
  int lane = t & 63, wid = t >> 6;
  int m0 = blockIdx.x * BM;
  int rows_valid = min(BM, N - m0);

  int eb = rowptr[m0];
  int ne = min(rowptr[min(m0 + BM, N)] - eb, CAP);

  if (t <= BM) rs[t] = rowptr[min(m0 + t, N)];
  if (t < BM)  y_r[t] = (t < rows_valid) ? y[m0 + t] : 0.f;
  for (int j = t; j < ne; j += 512){
    int2 e = ev2[eb + j];
    evy[j] = make_float2(__int_as_float(e.y), y[e.x]);
  }
  __syncthreads();

  // ---- z phase: 8 rows per wave, 8 channels per lane, uniform edges
  {
    float w1v[8], b1v[8];
    *(float4*)&w1v[0] = *(const float4*)(W1 + lane*8);
    *(float4*)&w1v[4] = *(const float4*)(W1 + lane*8 + 4);
    *(float4*)&b1v[0] = *(const float4*)(b1 + lane*8);
    *(float4*)&b1v[4] = *(const float4*)(b1 + lane*8 + 4);
    #pragma unroll
    for (int r8 = 0; r8 < 8; ++r8){
      int r = wid*8 + r8;
      int jb = min(rs[r] - eb, ne), je = min(rs[r+1] - eb, ne);
      float acc[8] = {0,0,0,0,0,0,0,0};
      int j = jb;
      for (; j + 4 <= je; j += 4){
        float2 e0 = evy[j], e1 = evy[j+1], e2 = evy[j+2], e3 = evy[j+3];
        #pragma unroll
        for (int k = 0; k < 8; ++k){
          float s0 = fmaf(e0.y, w1v[k], b1v[k]);
          acc[k] = fmaf(e0.x, fmaxf(s0, 0.01f*s0), acc[k]);
          float s1 = fmaf(e1.y, w1v[k], b1v[k]);
          acc[k] = fmaf(e1.x, fmaxf(s1, 0.01f*s1), acc[k]);
          float s2 = fmaf(e2.y, w1v[k], b1v[k]);
          acc[k] = fmaf(e2.x, fmaxf(s2, 0.01f*s2), acc[k]);
          float s3 = fmaf(e3.y, w1v[k], b1v[k]);
          acc[k] = fmaf(e3.x, fmaxf(s3, 0.01f*s3), acc[k]);
        }
      }
      for (; j < je; ++j){
        float2 e = evy[j];
        #pragma unroll
        for (int k = 0; k < 8; ++k){
          float s = fmaf(e.y, w1v[k], b1v[k]);
          acc[k] = fmaf(e.x, fmaxf(s, 0.01f*s), acc[k]);
        }
      }
      float yr = y_r[r];
      u16x8 o;
      #pragma unroll
      for (int k = 0; k < 8; ++k) o[k] = f2bf(acc[k] + yr);
      int off = r*1024 + ((lane*16) ^ ((r & 7) << 4));
      *(u16x8*)(zlds + off) = o;
    }
  }
  __syncthreads();

  // ---- GEMM phase: NO barriers; A LDS-resident, B streams from L2
  int r15 = lane & 15, rg = lane >> 4;
  int nc = wid * 64;
  int swz = (r15 & 7) << 4;
  f32x4 acc[4][4] = {};
  const u16* bp = wct + (size_t)(nc + r15)*H + rg*8;

  #pragma unroll 2
  for (int kt = 0; kt < 16; ++kt){
    s16x8 af[4], bf[4];
    #pragma unroll
    for (int m = 0; m < 4; ++m){
      int off = (m*16 + r15)*1024 + ((kt*64 + rg*16) ^ swz);
      af[m] = *(const s16x8*)(zlds + off);
    }
    #pragma unroll
    for (int n = 0; n < 4; ++n)
      bf[n] = *(const s16x8*)(bp + (size_t)n*16*H + kt*32);
    #pragma unroll
    for (int m = 0; m < 4; ++m)
      #pragma unroll
      for (int n = 0; n < 4; ++n)
        acc[m][n] = __builtin_amdgcn_mfma_f32_16x16x32_bf16(af[m], bf[n], acc[m][n], 0,0,0);
  }

  // ---- epilogue: leaky(acc+bc) colsum + x1-pool, one atomic per (blk,ch)
  float yrow[16];
  #pragma unroll
  for (int i = 0; i < 16; ++i) yrow[i] = y_r[rg*16 + i];
  int nvalid = rows_valid - rg*16;   // rows rg*16+i valid iff i < nvalid

  #pragma unroll
  for (int n = 0; n < 4; ++n){
    int gc = nc + n*16 + r15;
    float bcv = bc[gc], w1c = W1[gc], b1c = b1[gc];
    float cs = 0.f;
    #pragma unroll
    for (int m = 0; m < 4; ++m){
      int r0 = m*16 + rg*4;
      #pragma unroll
      for (int j = 0; j < 4; ++j){
        if (r0 + j < rows_valid){
          float wv2 = acc[m][n][j] + bcv;
          cs += fmaxf(wv2, 0.01f*wv2);
        }
      }
    }
    #pragma unroll
    for (int i = 0; i < 16; ++i){
      if (i < nvalid){
        float v = fmaf(yrow[i], w1c, b1c);
        cs += fmaxf(v, 0.01f*v);
      }
    }
    cs += __shfl_xor(cs, 16);
    cs += __shfl_xor(cs, 32);
    if (rg == 0) atomicAdd(&pooled_acc[gc], cs);
  }
}

// ------- gamma/beta heads (finalizes pooled locally): 1 wave / row ------
__global__ __launch_bounds__(256) void k_heads(const float* __restrict__ pooled_acc,
        const float* __restrict__ Sx,
        const float* __restrict__ Wg, const float* __restrict__ bg,
        const float* __restrict__ Wb, const float* __restrict__ bb,
        float* __restrict__ out, float invN){
  __shared__ float sp[H];
  int t = threadIdx.x;
  float sx = Sx[0];
  sp[t]     = (pooled_acc[t]     + sx) * invN;
  sp[t+256] = (pooled_acc[t+256] + sx) * invN;
  __syncthreads();
  int wid = t >> 6, l = t & 63;
  int o = blockIdx.x*4 + wid;           // 0..6143
  int head = o / (NLAYERS*OUTF);        // 0=gamma 1=beta
  int rem  = o - head*(NLAYERS*OUTF);
  const float* W = (head ? Wb : Wg) + (size_t)rem * H;
  float4 wa = *(const float4*)(W + l*8);
  float4 wb = *(const float4*)(W + l*8 + 4);
  float4 pa = *(const float4*)(sp + l*8);
  float4 pb = *(const float4*)(sp + l*8 + 4);
  float acc = wa.x*pa.x + wa.y*pa.y + wa.z*pa.z + wa.w*pa.w
            + wb.x*pb.x + wb.y*pb.y + wb.z*pb.z + wb.w*pb.w;
  #pragma unroll
  for (int off=32; off; off>>=1) acc += __shfl_xor(acc, off);
  if (l == 0) out[o] = acc + (head ? bb : bg)[rem];
}

extern "C" void kernel_launch(void* const* d_in, const int* in_sizes, int n_in,
                              void* d_out, int out_size, void* d_ws, size_t ws_size,
                              hipStream_t stream){
  const float* sst      = (const float*)d_in[0];
  const int*   node_idx = (const int*)d_in[1];
  const int*   arows    = (const int*)d_in[2];
  const int*   acols    = (const int*)d_in[3];
  const float* avals    = (const float*)d_in[4];
  const float* W1       = (const float*)d_in[5];
  const float* b1       = (const float*)d_in[6];
  const float* Wc       = (const float*)d_in[7];
  const float* bc       = (const float*)d_in[8];
  const float* Wg       = (const float*)d_in[9];
  const float* bg       = (const float*)d_in[10];
  const float* Wb       = (const float*)d_in[11];
  const float* bb       = (const float*)d_in[12];

  const int N = in_sizes[1];
  const int E = in_sizes[2];

  char* w = (char*)d_ws;
  size_t off = 0;
  auto take = [&](size_t b)->char*{ char* p = w + off; off += (b + 255) & ~(size_t)255; return p; };

  size_t zero_words = (size_t)2*N + H + 1;     // y | counts | pooled_acc | Sx
  float* y          = (float*)take(zero_words*4);
  int*   counts     = (int*)(y + N);
  float* pooled_acc = y + 2*N;
  float* Sx         = pooled_acc + H;
  float* x0         = (float*)take((size_t)N*4);
  int*   rowptr     = (int*)take((size_t)(N+1)*4);
  int*   cursor     = (int*)take((size_t)N*4);
  int2*  ev2        = (int2*)take((size_t)E*8);
  u16*   wct        = (u16*)take((size_t)H*H*2);

  hipMemsetAsync(y, 0, zero_words*4, stream);

  int nbx0 = (N + 255)/256;
  int nbhist = (E + 255)/256;
  k_pre  <<<nbx0 + 256 + nbhist, 256, 0, stream>>>(sst, node_idx, x0, Sx,
                                                   Wc, wct, arows, counts, N, E, nbx0);
  k_scan <<<1, 1024, 0, stream>>>(counts, rowptr, cursor, N);
  k_fill <<<(E+255)/256, 256, 0, stream>>>(arows, acols, avals, x0, cursor, y, ev2, E);
  int nblk = (N + BM - 1) / BM;
  k_fused<<<nblk, 512, 0, stream>>>(rowptr, ev2, y, W1, b1, wct, bc, pooled_acc, N);
  k_heads<<<(2*NLAYERS*OUTF)/4, 256, 0, stream>>>(pooled_acc, Sx, Wg, bg, Wb, bb,
                                                  (float*)d_out, 1.0f/(float)N);
}